// Round 5
// baseline (151.796 us; speedup 1.0000x reference)
//
#include <hip/hip_runtime.h>

typedef __attribute__((ext_vector_type(8))) __bf16 bf16x8;
typedef __attribute__((ext_vector_type(4))) float f32x4;
typedef __attribute__((ext_vector_type(16))) float f32x16;
typedef __attribute__((ext_vector_type(8))) unsigned short u16x8;

#define MFMA16(a, b, c) __builtin_amdgcn_mfma_f32_16x16x32_bf16((a), (b), (c), 0, 0, 0)
#define MFMA32(a, b, c) __builtin_amdgcn_mfma_f32_32x32x16_bf16((a), (b), (c), 0, 0, 0)

// async global->LDS, 16B per lane; dst must be wave-uniform base (lane*16B auto)
#define GLDS16(g, l) __builtin_amdgcn_global_load_lds( \
    (const __attribute__((address_space(1))) unsigned int*)(const void*)(g), \
    (__attribute__((address_space(3))) unsigned int*)(void*)(l), 16, 0, 0)

__device__ __forceinline__ unsigned short bfc(float f) {
    __bf16 h = (__bf16)f;
    return __builtin_bit_cast(unsigned short, h);
}
__device__ __forceinline__ float bf2f(unsigned short u) {
    return __builtin_bit_cast(float, (unsigned int)u << 16);
}

// ---------------------------------------------------------------- convert f32 -> bf16
__global__ void convert_f32_bf16(const float* __restrict__ src, unsigned short* __restrict__ dst, int n4) {
    int i = blockIdx.x * blockDim.x + threadIdx.x;
    if (i < n4) {
        float4 v = reinterpret_cast<const float4*>(src)[i];
        ushort4 o;
        o.x = bfc(v.x); o.y = bfc(v.y); o.z = bfc(v.z); o.w = bfc(v.w);
        reinterpret_cast<ushort4*>(dst)[i] = o;
    }
}

// ---------------------------------------------------------------- WkE / WvF fold
__global__ __launch_bounds__(256) void build_wkev(
    const float* __restrict__ Wk, const float* __restrict__ Wv,
    const float* __restrict__ E, const float* __restrict__ F,
    unsigned short* __restrict__ wcat) {
    __shared__ float Els[4096];          // E_h: [64 d][64 kk] f32
    const int bx = blockIdx.x;           // 256 blocks
    const int sel = bx >> 7, h = (bx >> 3) & 15, cs = bx & 7;
    const int tid = threadIdx.x;
    const int ko = tid >> 5, cq = tid & 31;
    const int c = cs * 128 + cq * 4;

    const float* W  = sel ? Wv : Wk;
    const float* Ef = (sel ? F : E) + (size_t)h * 4096;
#pragma unroll
    for (int i = tid; i < 1024; i += 256)
        reinterpret_cast<float4*>(Els)[i] = reinterpret_cast<const float4*>(Ef)[i];
    __syncthreads();

    float acc[8][4];
#pragma unroll
    for (int j = 0; j < 8; ++j)
#pragma unroll
        for (int t = 0; t < 4; ++t) acc[j][t] = 0.f;

#pragma unroll 4
    for (int d = 0; d < 64; ++d) {
        float4 wv4 = *reinterpret_cast<const float4*>(&W[(size_t)(h * 64 + d) * 1024 + c]);
        float4 e0 = *reinterpret_cast<const float4*>(&Els[d * 64 + ko * 8]);
        float4 e1 = *reinterpret_cast<const float4*>(&Els[d * 64 + ko * 8 + 4]);
        float ev[8] = {e0.x, e0.y, e0.z, e0.w, e1.x, e1.y, e1.z, e1.w};
#pragma unroll
        for (int j = 0; j < 8; ++j) {
            acc[j][0] = fmaf(ev[j], wv4.x, acc[j][0]);
            acc[j][1] = fmaf(ev[j], wv4.y, acc[j][1]);
            acc[j][2] = fmaf(ev[j], wv4.z, acc[j][2]);
            acc[j][3] = fmaf(ev[j], wv4.w, acc[j][3]);
        }
    }
#pragma unroll
    for (int j = 0; j < 8; ++j) {
        const int row = 1024 + (sel << 10) + h * 64 + ko * 8 + j;
        ushort4 o;
        o.x = bfc(acc[j][0]); o.y = bfc(acc[j][1]); o.z = bfc(acc[j][2]); o.w = bfc(acc[j][3]);
        *reinterpret_cast<ushort4*>(&wcat[(size_t)row * 1024 + c]) = o;
    }
}

// ---------------------------------------------------------------- bf16 GEMM, B^T layout
template <int MODE>
__global__ __launch_bounds__(256) void gemm_bt(
    const unsigned short* __restrict__ A, const unsigned short* __restrict__ Bt, int K,
    unsigned short* __restrict__ qo, unsigned short* __restrict__ kpo, unsigned short* __restrict__ vpto,
    float* __restrict__ out, const float* __restrict__ bp) {
    __shared__ __align__(16) unsigned short As[128 * 32];
    __shared__ __align__(16) unsigned short Bs[128 * 32];
    const int tid = threadIdx.x;
    const int lane = tid & 63, wv = tid >> 6;
    const int g = lane >> 4, ln = lane & 15;
    const int wm = wv >> 1, wn = wv & 1;
    const int m0 = blockIdx.x * 128, n0 = blockIdx.y * 128;
    const int wvb = wv * 512;

    f32x4 acc[4][4];
#pragma unroll
    for (int i = 0; i < 4; ++i)
#pragma unroll
        for (int j = 0; j < 4; ++j) acc[i][j] = (f32x4){0.f, 0.f, 0.f, 0.f};

    const int c0 = tid, c1 = 256 + tid;
    const int row0 = c0 >> 2, k80 = c0 & 3;
    const int row1 = c1 >> 2, k81 = c1 & 3;

    const int nk = K >> 5;
    for (int kt = 0; kt < nk; ++kt) {
        const int kb = kt * 32;
        __syncthreads();
        GLDS16(A  + (size_t)(m0 + row0) * K + kb + k80 * 8, As + wvb);
        GLDS16(A  + (size_t)(m0 + row1) * K + kb + k81 * 8, As + 2048 + wvb);
        GLDS16(Bt + (size_t)(n0 + row0) * K + kb + k80 * 8, Bs + wvb);
        GLDS16(Bt + (size_t)(n0 + row1) * K + kb + k81 * 8, Bs + 2048 + wvb);
        __syncthreads();
        bf16x8 af[4], bfr[4];
#pragma unroll
        for (int i = 0; i < 4; ++i)
            af[i] = __builtin_bit_cast(bf16x8, *reinterpret_cast<const u16x8*>(As + (wm * 64 + i * 16 + ln) * 32 + g * 8));
#pragma unroll
        for (int j = 0; j < 4; ++j)
            bfr[j] = __builtin_bit_cast(bf16x8, *reinterpret_cast<const u16x8*>(Bs + (wn * 64 + j * 16 + ln) * 32 + g * 8));
#pragma unroll
        for (int i = 0; i < 4; ++i)
#pragma unroll
            for (int j = 0; j < 4; ++j)
                acc[i][j] = MFMA16(af[i], bfr[j], acc[i][j]);
    }

#pragma unroll
    for (int i = 0; i < 4; ++i) {
        const int mbase = m0 + wm * 64 + i * 16 + 4 * g;
#pragma unroll
        for (int j = 0; j < 4; ++j) {
            const int ncol = n0 + wn * 64 + j * 16 + ln;
#pragma unroll
            for (int r = 0; r < 4; ++r) {
                const int m = mbase + r;
                if (MODE == 0) {
                    const int b = m >> 11, t = m & 2047;
                    const int sec = ncol >> 10, nn = ncol & 1023;
                    const int h = nn >> 6, e = nn & 63;
                    const int bh = b * 16 + h;
                    unsigned short val = bfc(acc[i][j][r]);
                    if (sec == 0)      qo[(size_t)(bh * 2048 + t) * 64 + e] = val;
                    else if (sec == 1) kpo[(size_t)(bh * 2048 + t) * 64 + e] = val;
                    else               vpto[(size_t)(bh * 64 + e) * 2048 + t] = val;
                } else {
                    out[(size_t)m * 1024 + ncol] = acc[i][j][r] + bp[ncol];
                }
            }
        }
    }
}

// ---------------------------------------------------------------- split-K flash attention, phase A
// WU = (bh, qt, chunk of <=8 KV tiles). 2 waves x 32 q-rows, 32x32 MFMA, in-register P.
// Writes un-normalized O-partial (bf16 [64q][64d]) + m,l (f32) per WU.
__global__ __launch_bounds__(128, 2) void attn_part(
    const unsigned short* __restrict__ qg, const unsigned short* __restrict__ kpg,
    const unsigned short* __restrict__ vptg,
    unsigned short* __restrict__ pO, float* __restrict__ pML) {
    const int bx = blockIdx.x;                    // [0,2560)
    const int xcd = bx & 7;
    const int j = bx >> 3;                        // [0,320)
    const int urev = j >> 2, bhl = j & 3;
    const int bh = xcd * 4 + bhl;                 // 4 heads per XCD
    const int u = 79 - urev;                      // long q-tiles dispatched first
    int qt, c;
    if (u < 8)       { qt = u;                  c = 0; }
    else if (u < 24) { qt = 8 + ((u - 8) >> 1); c = (u - 8) & 1; }
    else if (u < 48) { qt = 16 + (u - 24) / 3;  c = (u - 24) % 3; }
    else             { qt = 24 + ((u - 48) >> 2); c = (u - 48) & 3; }
    const int stBeg = c * 8;
    const int qe = qt + 1;
    const int stEnd = (stBeg + 8 < qe) ? stBeg + 8 : qe;   // exclusive
    const int wu = bh * 80 + u;

    const int tid = threadIdx.x;
    const int wv = tid >> 6, lane = tid & 63;
    const int r31 = lane & 31, hi = lane >> 5, l7 = lane & 7;

    __shared__ __align__(16) unsigned short kps[2][4096];   // [64 s][8 chunks swz]
    __shared__ __align__(16) unsigned short vps[2][4096];   // [64 v][8 chunks swz]

    const unsigned short* kbase = kpg  + (size_t)bh * 131072;
    const unsigned short* vbase = vptg + (size_t)bh * 131072;

    const int qrow = qt * 64 + wv * 32 + r31;
    const unsigned short* qp = qg + ((size_t)bh * 2048 + qrow) * 64 + 8 * hi;
    bf16x8 qf[4];
#pragma unroll
    for (int w = 0; w < 4; ++w)
        qf[w] = __builtin_bit_cast(bf16x8, *reinterpret_cast<const u16x8*>(qp + 16 * w));

    f32x16 oT0 = {0,0,0,0,0,0,0,0,0,0,0,0,0,0,0,0};
    f32x16 oT1 = {0,0,0,0,0,0,0,0,0,0,0,0,0,0,0,0};
    float mrow = -1e30f, lacc = 0.f;
    const float L2E = 1.44269504f;
    const float CS  = 0.18033688f;     // 0.125 * log2(e)

    auto stage = [&](int buf, int st) {
        const int s0 = st * 64;
#pragma unroll
        for (int rep = 0; rep < 4; ++rep) {
            const int row = rep * 16 + wv * 8 + (lane >> 3);
            const int cg = (lane & 7) ^ (lane >> 3);
            GLDS16(kbase + (size_t)(s0 + row) * 64 + cg * 8, &kps[buf][(rep * 16 + wv * 8) * 64]);
            GLDS16(vbase + (size_t)row * 2048 + s0 + cg * 8, &vps[buf][(rep * 16 + wv * 8) * 64]);
        }
    };

    stage(0, stBeg);
    for (int st = stBeg; st < stEnd; ++st) {
        const int cur = (st - stBeg) & 1;
        __syncthreads();
        if (st + 1 < stEnd) stage(cur ^ 1, st + 1);

        const bool diag = (st == qt);
        const bool skip1 = diag && (wv == 0);

        f32x16 sA0 = {0,0,0,0,0,0,0,0,0,0,0,0,0,0,0,0};
        f32x16 sA1 = {0,0,0,0,0,0,0,0,0,0,0,0,0,0,0,0};
#pragma unroll
        for (int w = 0; w < 4; ++w) {
            bf16x8 k0 = __builtin_bit_cast(bf16x8, *reinterpret_cast<const u16x8*>(
                &kps[cur][r31 * 64 + (((2 * w + hi) ^ l7) * 8)]));
            sA0 = MFMA32(k0, qf[w], sA0);
        }
        if (!skip1) {
#pragma unroll
            for (int w = 0; w < 4; ++w) {
                bf16x8 k1 = __builtin_bit_cast(bf16x8, *reinterpret_cast<const u16x8*>(
                    &kps[cur][(32 + r31) * 64 + (((2 * w + hi) ^ l7) * 8)]));
                sA1 = MFMA32(k1, qf[w], sA1);
            }
        }

        if (diag) {
#pragma unroll
            for (int reg = 0; reg < 16; ++reg) {
                const int oc = (reg & 3) + 8 * (reg >> 2);
                if (wv == 0) { if (oc + 4 * hi > r31) sA0[reg] = -3e38f; }
                else         { if (oc + 4 * hi > r31) sA1[reg] = -3e38f; }
            }
        }

        float mp = sA0[0];
#pragma unroll
        for (int reg = 1; reg < 16; ++reg) mp = fmaxf(mp, sA0[reg]);
        if (!skip1) {
#pragma unroll
            for (int reg = 0; reg < 16; ++reg) mp = fmaxf(mp, sA1[reg]);
        }
        mp = fmaxf(mp, __shfl_xor(mp, 32));
        mp *= 0.125f;

        if (__any(mp - mrow > 8.0f)) {
            const float mn = fmaxf(mrow, mp);
            const float al = __builtin_exp2f((mrow - mn) * L2E);
            mrow = mn;
#pragma unroll
            for (int reg = 0; reg < 16; ++reg) { oT0[reg] *= al; oT1[reg] *= al; }
            lacc *= al;
        }
        const float t2 = mrow * L2E;

        float p0[16], p1[16];
#pragma unroll
        for (int reg = 0; reg < 16; ++reg) p0[reg] = __builtin_exp2f(fmaf(sA0[reg], CS, -t2));
        float ls0 = 0.f, ls1 = 0.f, ls2 = 0.f, ls3 = 0.f;
#pragma unroll
        for (int reg = 0; reg < 16; reg += 4) {
            ls0 += p0[reg]; ls1 += p0[reg + 1]; ls2 += p0[reg + 2]; ls3 += p0[reg + 3];
        }
        if (!skip1) {
#pragma unroll
            for (int reg = 0; reg < 16; ++reg) p1[reg] = __builtin_exp2f(fmaf(sA1[reg], CS, -t2));
#pragma unroll
            for (int reg = 0; reg < 16; reg += 4) {
                ls0 += p1[reg]; ls1 += p1[reg + 1]; ls2 += p1[reg + 2]; ls3 += p1[reg + 3];
            }
        }
        float ls = (ls0 + ls1) + (ls2 + ls3);
        ls += __shfl_xor(ls, 32);
        lacc += ls;

        unsigned int w0[8], w1[8];
#pragma unroll
        for (int i = 0; i < 8; ++i)
            asm("v_cvt_pk_bf16_f32 %0, %1, %2" : "=v"(w0[i]) : "v"(p0[2 * i]), "v"(p0[2 * i + 1]));
        asm volatile("v_permlane32_swap_b32 %0, %1" : "+v"(w0[0]), "+v"(w0[2]));
        asm volatile("v_permlane32_swap_b32 %0, %1" : "+v"(w0[1]), "+v"(w0[3]));
        asm volatile("v_permlane32_swap_b32 %0, %1" : "+v"(w0[4]), "+v"(w0[6]));
        asm volatile("v_permlane32_swap_b32 %0, %1" : "+v"(w0[5]), "+v"(w0[7]));
        if (!skip1) {
#pragma unroll
            for (int i = 0; i < 8; ++i)
                asm("v_cvt_pk_bf16_f32 %0, %1, %2" : "=v"(w1[i]) : "v"(p1[2 * i]), "v"(p1[2 * i + 1]));
            asm volatile("v_permlane32_swap_b32 %0, %1" : "+v"(w1[0]), "+v"(w1[2]));
            asm volatile("v_permlane32_swap_b32 %0, %1" : "+v"(w1[1]), "+v"(w1[3]));
            asm volatile("v_permlane32_swap_b32 %0, %1" : "+v"(w1[4]), "+v"(w1[6]));
            asm volatile("v_permlane32_swap_b32 %0, %1" : "+v"(w1[5]), "+v"(w1[7]));
        }

#pragma unroll
        for (int w = 0; w < 2; ++w) {
            bf16x8 pa = __builtin_bit_cast(bf16x8, (uint4){w0[4 * w], w0[4 * w + 1], w0[4 * w + 2], w0[4 * w + 3]});
            bf16x8 v0 = __builtin_bit_cast(bf16x8, *reinterpret_cast<const u16x8*>(
                &vps[cur][r31 * 64 + (((2 * w + hi) ^ l7) * 8)]));
            oT0 = MFMA32(v0, pa, oT0);
            bf16x8 v1 = __builtin_bit_cast(bf16x8, *reinterpret_cast<const u16x8*>(
                &vps[cur][(32 + r31) * 64 + (((2 * w + hi) ^ l7) * 8)]));
            oT1 = MFMA32(v1, pa, oT1);
        }
        if (!skip1) {
#pragma unroll
            for (int w = 2; w < 4; ++w) {
                bf16x8 pa = __builtin_bit_cast(bf16x8, (uint4){w1[4 * (w - 2)], w1[4 * (w - 2) + 1], w1[4 * (w - 2) + 2], w1[4 * (w - 2) + 3]});
                bf16x8 v0 = __builtin_bit_cast(bf16x8, *reinterpret_cast<const u16x8*>(
                    &vps[cur][r31 * 64 + (((2 * w + hi) ^ l7) * 8)]));
                oT0 = MFMA32(v0, pa, oT0);
                bf16x8 v1 = __builtin_bit_cast(bf16x8, *reinterpret_cast<const u16x8*>(
                    &vps[cur][(32 + r31) * 64 + (((2 * w + hi) ^ l7) * 8)]));
                oT1 = MFMA32(v1, pa, oT1);
            }
        }
    }

    // ---- epilogue: LDS-transpose O^T -> [q][d] bf16, store partial + (m,l)
    __syncthreads();
    unsigned int* tr = reinterpret_cast<unsigned int*>(wv ? (void*)kps[1] : (void*)kps[0]);  // [32 q][33] u32
#pragma unroll
    for (int i = 0; i < 8; ++i) {
        unsigned int wda, wdb;
        asm("v_cvt_pk_bf16_f32 %0, %1, %2" : "=v"(wda) : "v"(oT0[2 * i]), "v"(oT0[2 * i + 1]));
        asm("v_cvt_pk_bf16_f32 %0, %1, %2" : "=v"(wdb) : "v"(oT1[2 * i]), "v"(oT1[2 * i + 1]));
        const int col = (i & 1) + 4 * (i >> 1) + 2 * hi;
        tr[r31 * 33 + col] = wda;
        tr[r31 * 33 + 16 + col] = wdb;
    }
    const size_t gb = (size_t)wu * 4096 + (size_t)(wv * 32 + r31) * 64 + 32 * hi;
#pragma unroll
    for (int cc = 0; cc < 4; ++cc) {
        uint4 v = *reinterpret_cast<uint4*>(&tr[r31 * 33 + 16 * hi + 4 * cc]);
        *reinterpret_cast<uint4*>(&pO[gb + 8 * cc]) = v;
    }
    if (hi == 0) {
        pML[(size_t)wu * 128 + wv * 32 + r31] = mrow;
        pML[(size_t)wu * 128 + 64 + wv * 32 + r31] = lacc;
    }
}

// ---------------------------------------------------------------- split-K attention, phase B (merge)
// block = (bh, qt): combine nc<=4 chunks; write o [b][t][h*64+d] bf16.
__global__ __launch_bounds__(256) void attn_merge(
    const unsigned short* __restrict__ pO, const float* __restrict__ pML,
    unsigned short* __restrict__ og) {
    const int bx = blockIdx.x;             // [0,1024)
    const int xcd = bx & 7, j = bx >> 3;   // [0,128)
    const int bhl = j & 3, qt = j >> 2;
    const int bh = xcd * 4 + bhl;
    const int nc = (qt >> 3) + 1;
    int ubase;
    if (qt < 8)       ubase = qt;
    else if (qt < 16) ubase = 8 + (qt - 8) * 2;
    else if (qt < 24) ubase = 24 + (qt - 16) * 3;
    else              ubase = 48 + (qt - 24) * 4;
    const int wu0 = bh * 80 + ubase;

    __shared__ float winv[4][64];
    const int tid = threadIdx.x;
    if (tid < 64) {
        float m[4], l[4];
        float M = -3e38f;
#pragma unroll
        for (int c2 = 0; c2 < 4; ++c2) {
            if (c2 < nc) {
                m[c2] = pML[(size_t)(wu0 + c2) * 128 + tid];
                l[c2] = pML[(size_t)(wu0 + c2) * 128 + 64 + tid];
            } else { m[c2] = -3e38f; l[c2] = 0.f; }
            M = fmaxf(M, m[c2]);
        }
        float L = 0.f;
        float w[4];
#pragma unroll
        for (int c2 = 0; c2 < 4; ++c2) {
            w[c2] = (c2 < nc) ? __builtin_exp2f((m[c2] - M) * 1.44269504f) : 0.f;
            L = fmaf(w[c2], l[c2], L);
        }
        const float invL = 1.0f / L;
#pragma unroll
        for (int c2 = 0; c2 < 4; ++c2) winv[c2][tid] = w[c2] * invL;
    }
    __syncthreads();

    const int q = tid >> 2, dc = tid & 3;    // 16-d chunk per thread
    float acc[16];
#pragma unroll
    for (int i = 0; i < 16; ++i) acc[i] = 0.f;
#pragma unroll
    for (int c2 = 0; c2 < 4; ++c2) {
        if (c2 < nc) {
            const unsigned short* src = pO + (size_t)(wu0 + c2) * 4096 + q * 64 + dc * 16;
            const float wc = winv[c2][q];
            u16x8 v0 = *reinterpret_cast<const u16x8*>(src);
            u16x8 v1 = *reinterpret_cast<const u16x8*>(src + 8);
#pragma unroll
            for (int i = 0; i < 8; ++i) {
                acc[i]     = fmaf(wc, bf2f(v0[i]), acc[i]);
                acc[8 + i] = fmaf(wc, bf2f(v1[i]), acc[8 + i]);
            }
        }
    }
    const int b = bh >> 4, h = bh & 15;
    const int t = qt * 64 + q;
    unsigned short* dst = og + ((size_t)(b * 2048 + t)) * 1024 + h * 64 + dc * 16;
    ushort4 o0, o1, o2, o3;
    o0.x = bfc(acc[0]);  o0.y = bfc(acc[1]);  o0.z = bfc(acc[2]);  o0.w = bfc(acc[3]);
    o1.x = bfc(acc[4]);  o1.y = bfc(acc[5]);  o1.z = bfc(acc[6]);  o1.w = bfc(acc[7]);
    o2.x = bfc(acc[8]);  o2.y = bfc(acc[9]);  o2.z = bfc(acc[10]); o2.w = bfc(acc[11]);
    o3.x = bfc(acc[12]); o3.y = bfc(acc[13]); o3.z = bfc(acc[14]); o3.w = bfc(acc[15]);
    reinterpret_cast<ushort4*>(dst)[0] = o0;
    reinterpret_cast<ushort4*>(dst)[1] = o1;
    reinterpret_cast<ushort4*>(dst)[2] = o2;
    reinterpret_cast<ushort4*>(dst)[3] = o3;
}

// ---------------------------------------------------------------- launch
extern "C" void kernel_launch(void* const* d_in, const int* in_sizes, int n_in,
                              void* d_out, int out_size, void* d_ws, size_t ws_size,
                              hipStream_t stream) {
    const float* x  = (const float*)d_in[0];
    const float* Wq = (const float*)d_in[1];
    const float* Wk = (const float*)d_in[2];
    const float* Wv = (const float*)d_in[3];
    const float* E  = (const float*)d_in[4];
    const float* F  = (const float*)d_in[5];
    const float* Wp = (const float*)d_in[6];
    const float* bp = (const float*)d_in[7];
    float* out = (float*)d_out;

    char* ws = (char*)d_ws;
    unsigned short* qw   = (unsigned short*)(ws);               // [32][2048][64] bf16 (8 MB)
    unsigned short* kpw  = (unsigned short*)(ws + 8388608);     // [32][2048][64] bf16 (8 MB)
    unsigned short* vptw = (unsigned short*)(ws + 16777216);    // [32][64][2048] bf16 (8 MB)
    unsigned short* ow   = (unsigned short*)(ws + 25165824);    // 4096x1024 bf16 (8 MB)
    unsigned short* wpb  = (unsigned short*)(ws + 33554432);    // 1024x1024 bf16 (2 MB)
    unsigned short* xb   = (unsigned short*)(ws + 35651584);    // 4096x1024 bf16 (8 MB)  [dead after gemm0]
    unsigned short* wcat = (unsigned short*)(ws + 44040192);    // 3072x1024 bf16 (6 MB)  [dead after gemm0]
    unsigned short* pO   = (unsigned short*)(ws + 35651584);    // 2560x4096 bf16 (21 MB) [overlays xb/wcat]
    float*          pML  = (float*)(ws + 56623104);             // 2560x128 f32 (1.3 MB)

    convert_f32_bf16<<<4096, 256, 0, stream>>>(x, xb, 1048576);
    convert_f32_bf16<<<1024, 256, 0, stream>>>(Wq, wcat, 262144);
    convert_f32_bf16<<<1024, 256, 0, stream>>>(Wp, wpb, 262144);
    build_wkev<<<256, 256, 0, stream>>>(Wk, Wv, E, F, wcat);
    gemm_bt<0><<<dim3(32, 24), 256, 0, stream>>>(xb, wcat, 1024, qw, kpw, vptw, nullptr, nullptr);
    attn_part<<<2560, 128, 0, stream>>>(qw, kpw, vptw, pO, pML);
    attn_merge<<<1024, 256, 0, stream>>>(pO, pML, ow);
    gemm_bt<1><<<dim3(32, 8), 256, 0, stream>>>(ow, wpb, 1024, nullptr, nullptr, nullptr, out, bp);
}